// Round 1
// baseline (301.859 us; speedup 1.0000x reference)
//
#include <hip/hip_runtime.h>

namespace {

constexpr int D  = 1024;   // in_features
constexpr int KR = 64;     // num_experts * rank = 4*16
constexpr int O  = 1024;   // out_features
constexpr int TM = 64;     // rows per block
constexpr int KT = 128;    // K-chunk staged in LDS for phase 1

__device__ __forceinline__ float4 ldg4(const float* p) {
    return *reinterpret_cast<const float4*>(p);
}

// wt[kr][o] = up_w[k][o][r], kr = k*16 + r.  up_w flat: k*16384 + o*16 + r.
__global__ void __launch_bounds__(256) transpose_up_k(const float* __restrict__ uw,
                                                      float* __restrict__ wt) {
    const int k = blockIdx.x;      // 0..3
    const int t = threadIdx.x;
    for (int e = t; e < 16384; e += 256) {
        const int o = e >> 4;
        const int r = e & 15;
        wt[(k * 16 + r) * 1024 + o] = uw[k * 16384 + e];
    }
}

__global__ void __launch_bounds__(256) lora_fused_k(
        const float* __restrict__ hs,     // [4,4096,1024]
        const float* __restrict__ alpha,  // [4,4]
        const float* __restrict__ dw,     // [64][1024]  (k*16+r major)
        const float* __restrict__ wt,     // [64][1024]  transposed up_w
        float* __restrict__ out) {        // [4,4096,1024]
    __shared__ float A[TM][KT + 4];      // 64 x 132 = 33.8 KB
    __shared__ float LOW[TM][KR + 4];    // 64 x 68  = 17.4 KB

    const int t = threadIdx.x;
    const int row0 = blockIdx.x * TM;    // global row = b*4096 + n
    const int b = row0 >> 12;

    // ---------------- phase 1: low = hs @ dw^T, alpha*scale folded ----------------
    {
        const int ty  = t >> 3;          // 0..31 -> rows ty*2, ty*2+1
        const int tx  = t & 7;           // 0..7  -> kr = tx*8 .. tx*8+7
        const int r0  = ty * 2;
        const int kr0 = tx * 8;

        float acc[2][8];
#pragma unroll
        for (int i = 0; i < 2; ++i)
#pragma unroll
            for (int j = 0; j < 8; ++j) acc[i][j] = 0.f;

        for (int c = 0; c < D / KT; ++c) {
            const int dbase = c * KT;
            // stage A tile: 64 rows x 128 floats, coalesced float4
#pragma unroll
            for (int j2 = 0; j2 < 8; ++j2) {
                const int e  = j2 * 256 + t;
                const int ar = e >> 5;
                const int ac = (e & 31) * 4;
                const float4 v = ldg4(&hs[(long)(row0 + ar) * D + dbase + ac]);
                *reinterpret_cast<float4*>(&A[ar][ac]) = v;
            }
            __syncthreads();

#pragma unroll 2
            for (int dd = 0; dd < KT; dd += 4) {
                const float4 a0 = *reinterpret_cast<const float4*>(&A[r0][dd]);
                const float4 a1 = *reinterpret_cast<const float4*>(&A[r0 + 1][dd]);
#pragma unroll
                for (int j = 0; j < 8; ++j) {
                    const float4 bv = ldg4(&dw[(long)(kr0 + j) * D + dbase + dd]);
                    acc[0][j] = fmaf(a0.x, bv.x, acc[0][j]);
                    acc[0][j] = fmaf(a0.y, bv.y, acc[0][j]);
                    acc[0][j] = fmaf(a0.z, bv.z, acc[0][j]);
                    acc[0][j] = fmaf(a0.w, bv.w, acc[0][j]);
                    acc[1][j] = fmaf(a1.x, bv.x, acc[1][j]);
                    acc[1][j] = fmaf(a1.y, bv.y, acc[1][j]);
                    acc[1][j] = fmaf(a1.z, bv.z, acc[1][j]);
                    acc[1][j] = fmaf(a1.w, bv.w, acc[1][j]);
                }
            }
            __syncthreads();
        }

        // each thread's 8 kr values share one expert k = tx>>1
        const float sc = alpha[b * 4 + (tx >> 1)] * 4.0f;   // NETWORK_ALPHA/RANK = 4
#pragma unroll
        for (int i = 0; i < 2; ++i)
#pragma unroll
            for (int j = 0; j < 8; ++j)
                LOW[r0 + i][kr0 + j] = acc[i][j] * sc;
    }
    __syncthreads();

    // ---------------- phase 2: out = LOW @ wt ----------------
    {
        const int ty = t >> 4;           // 0..15 -> rows ty*4 .. +3
        const int tx = t & 15;           // 0..15 -> o-cols o0 .. o0+7
        const int r0 = ty * 4;
#pragma unroll 1
        for (int ot = 0; ot < O / 128; ++ot) {
            const int o0 = ot * 128 + tx * 8;
            float acc[4][8];
#pragma unroll
            for (int i = 0; i < 4; ++i)
#pragma unroll
                for (int j = 0; j < 8; ++j) acc[i][j] = 0.f;

#pragma unroll 2
            for (int k = 0; k < KR; k += 4) {
                float lr[4][4];
#pragma unroll
                for (int i = 0; i < 4; ++i) {
                    const float4 lv = *reinterpret_cast<const float4*>(&LOW[r0 + i][k]);
                    lr[i][0] = lv.x; lr[i][1] = lv.y; lr[i][2] = lv.z; lr[i][3] = lv.w;
                }
                float wr[4][8];
#pragma unroll
                for (int u = 0; u < 4; ++u) {
                    const float4 wa = ldg4(&wt[(long)(k + u) * O + o0]);
                    const float4 wb = ldg4(&wt[(long)(k + u) * O + o0 + 4]);
                    wr[u][0] = wa.x; wr[u][1] = wa.y; wr[u][2] = wa.z; wr[u][3] = wa.w;
                    wr[u][4] = wb.x; wr[u][5] = wb.y; wr[u][6] = wb.z; wr[u][7] = wb.w;
                }
#pragma unroll
                for (int u = 0; u < 4; ++u)
#pragma unroll
                    for (int i = 0; i < 4; ++i)
#pragma unroll
                        for (int j = 0; j < 8; ++j)
                            acc[i][j] = fmaf(lr[i][u], wr[u][j], acc[i][j]);
            }

#pragma unroll
            for (int i = 0; i < 4; ++i) {
                const float4 va = make_float4(acc[i][0], acc[i][1], acc[i][2], acc[i][3]);
                const float4 vb = make_float4(acc[i][4], acc[i][5], acc[i][6], acc[i][7]);
                float* po = &out[(long)(row0 + r0 + i) * O + o0];
                *reinterpret_cast<float4*>(po)     = va;
                *reinterpret_cast<float4*>(po + 4) = vb;
            }
        }
    }
}

} // namespace

extern "C" void kernel_launch(void* const* d_in, const int* in_sizes, int n_in,
                              void* d_out, int out_size, void* d_ws, size_t ws_size,
                              hipStream_t stream) {
    const float* hs    = (const float*)d_in[0];  // [4,4096,1024]
    const float* alpha = (const float*)d_in[1];  // [4,4]
    const float* dw    = (const float*)d_in[2];  // [4,16,1024] == [64][1024]
    const float* uw    = (const float*)d_in[3];  // [4,1024,16]
    float* wt   = (float*)d_ws;                  // 64*1024 floats = 256 KB scratch
    float* outp = (float*)d_out;

    hipLaunchKernelGGL(transpose_up_k, dim3(4),   dim3(256), 0, stream, uw, wt);
    hipLaunchKernelGGL(lora_fused_k,   dim3(256), dim3(256), 0, stream, hs, alpha, dw, wt, outp);
}

// Round 2
// 53.702 us; speedup vs baseline: 5.6211x; 5.6211x over previous
//
#include <hip/hip_runtime.h>

namespace {

typedef short  bf16x8 __attribute__((ext_vector_type(8)));
typedef float  f32x4  __attribute__((ext_vector_type(4)));

constexpr int D  = 1024;   // in_features
constexpr int O  = 1024;   // out_features

// fp32 -> bf16 bits, round-to-nearest-even
__device__ __forceinline__ short f2bf(float f) {
    unsigned u = __builtin_bit_cast(unsigned, f);
    u += 0x7fffu + ((u >> 16) & 1u);
    return (short)(u >> 16);
}

// Build bf16 operand buffers in ws:
//   dwb[kr][d]  = bf16(dw[kr][d])             (dw natural layout is [k*16+r][d])
//   wt2[o][kr]  = bf16(uw[k][o][r]), kr=k*16+r
__global__ void __launch_bounds__(256) prep_k(const float* __restrict__ dw,
                                              const float* __restrict__ uw,
                                              short* __restrict__ dwb,
                                              short* __restrict__ wt2) {
    const int idx = blockIdx.x * 256 + threadIdx.x;
    if (idx < 65536) {
        dwb[idx] = f2bf(dw[idx]);
    } else {
        const int e  = idx - 65536;   // e = o*64 + kr
        const int o  = e >> 6;
        const int kr = e & 63;
        const int k  = kr >> 4, r = kr & 15;
        wt2[e] = f2bf(uw[k * 16384 + o * 16 + r]);
    }
}

// Fused: low = hs @ dw^T (alpha*4 folded, bf16 in LDS), out = low @ wt2^T
// 256 threads = 4 waves; wave w owns rows [blk*64 + 16w, +16).
__global__ void __launch_bounds__(256) lora_mfma_k(
        const float* __restrict__ hs,     // [16384][1024] f32
        const float* __restrict__ alpha,  // [4][4]
        const short* __restrict__ dwb,    // [64][1024] bf16
        const short* __restrict__ wt2,    // [1024][64] bf16
        float* __restrict__ out) {        // [16384][1024] f32
    __shared__ __align__(16) short lowb[64][72];   // 72-stride: 16B-aligned rows, de-conflicted

    const int t    = threadIdx.x;
    const int w    = t >> 6;            // wave 0..3
    const int lane = t & 63;
    const int fr   = lane & 15;         // fragment row/col
    const int kg   = (lane >> 4) * 8;   // k-group offset within K=32
    const int rowblk = blockIdx.x * 64;
    const int b      = rowblk >> 12;    // batch (blocks never straddle)
    const int myrow  = rowblk + w * 16 + fr;
    const int lr0    = w * 16 + (lane >> 4) * 4;   // C-frag row base

    // ---------------- phase 1: low = hs @ dwb^T ----------------
    f32x4 acc[4];
#pragma unroll
    for (int nt = 0; nt < 4; ++nt) acc[nt] = (f32x4){0.f, 0.f, 0.f, 0.f};

    const float* ap = hs + (size_t)myrow * D + kg;
    const short* bp = dwb + fr * D + kg;

#pragma unroll 4
    for (int ks = 0; ks < 32; ++ks) {
        const float4 a0 = *reinterpret_cast<const float4*>(ap + ks * 32);
        const float4 a1 = *reinterpret_cast<const float4*>(ap + ks * 32 + 4);
        bf16x8 av;
        av[0] = f2bf(a0.x); av[1] = f2bf(a0.y); av[2] = f2bf(a0.z); av[3] = f2bf(a0.w);
        av[4] = f2bf(a1.x); av[5] = f2bf(a1.y); av[6] = f2bf(a1.z); av[7] = f2bf(a1.w);
#pragma unroll
        for (int nt = 0; nt < 4; ++nt) {
            const bf16x8 bv = *reinterpret_cast<const bf16x8*>(bp + nt * 16 * D + ks * 32);
            acc[nt] = __builtin_amdgcn_mfma_f32_16x16x32_bf16(av, bv, acc[nt], 0, 0, 0);
        }
    }

    // scale by alpha[b][expert]*4 (expert == n-tile), write bf16 low to LDS
#pragma unroll
    for (int nt = 0; nt < 4; ++nt) {
        const float sc = alpha[b * 4 + nt] * 4.0f;   // NETWORK_ALPHA/RANK = 4
#pragma unroll
        for (int j = 0; j < 4; ++j)
            lowb[lr0 + j][nt * 16 + fr] = f2bf(acc[nt][j] * sc);
    }
    __syncthreads();

    // ---------------- phase 2: out = low @ wt2^T ----------------
    const bf16x8 pa0 = *reinterpret_cast<const bf16x8*>(&lowb[w * 16 + fr][kg]);
    const bf16x8 pa1 = *reinterpret_cast<const bf16x8*>(&lowb[w * 16 + fr][32 + kg]);

    float* op = out + (size_t)(rowblk + lr0) * O;
    const short* wp = wt2 + fr * 64 + kg;

#pragma unroll 2
    for (int nt = 0; nt < 64; ++nt) {
        const bf16x8 b0 = *reinterpret_cast<const bf16x8*>(wp + nt * 1024);
        const bf16x8 b1 = *reinterpret_cast<const bf16x8*>(wp + nt * 1024 + 32);
        f32x4 c = (f32x4){0.f, 0.f, 0.f, 0.f};
        c = __builtin_amdgcn_mfma_f32_16x16x32_bf16(pa0, b0, c, 0, 0, 0);
        c = __builtin_amdgcn_mfma_f32_16x16x32_bf16(pa1, b1, c, 0, 0, 0);
#pragma unroll
        for (int j = 0; j < 4; ++j)
            op[(size_t)j * O + nt * 16 + fr] = c[j];
    }
}

} // namespace

extern "C" void kernel_launch(void* const* d_in, const int* in_sizes, int n_in,
                              void* d_out, int out_size, void* d_ws, size_t ws_size,
                              hipStream_t stream) {
    const float* hs    = (const float*)d_in[0];  // [4,4096,1024]
    const float* alpha = (const float*)d_in[1];  // [4,4]
    const float* dw    = (const float*)d_in[2];  // [4,16,1024]
    const float* uw    = (const float*)d_in[3];  // [4,1024,16]
    short* dwb = (short*)d_ws;                   // 128 KB
    short* wt2 = dwb + 65536;                    // 128 KB
    float* outp = (float*)d_out;

    hipLaunchKernelGGL(prep_k,      dim3(512), dim3(256), 0, stream, dw, uw, dwb, wt2);
    hipLaunchKernelGGL(lora_mfma_k, dim3(256), dim3(256), 0, stream, hs, alpha, dwb, wt2, outp);
}

// Round 3
// 51.419 us; speedup vs baseline: 5.8705x; 1.0444x over previous
//
#include <hip/hip_runtime.h>

namespace {

typedef short  bf16x8 __attribute__((ext_vector_type(8)));
typedef float  f32x4  __attribute__((ext_vector_type(4)));

constexpr int D  = 1024;   // in_features
constexpr int O  = 1024;   // out_features

// fp32 -> bf16 bits, round-to-nearest-even
__device__ __forceinline__ short f2bf(float f) {
    unsigned u = __builtin_bit_cast(unsigned, f);
    u += 0x7fffu + ((u >> 16) & 1u);
    return (short)(u >> 16);
}

// Build bf16 operand buffers in ws:
//   dwb[kr][d]  = bf16(dw[kr][d])             (dw natural layout is [k*16+r][d])
//   wt2[o][kr]  = bf16(uw[k][o][r]), kr=k*16+r
__global__ void __launch_bounds__(256) prep_k(const float* __restrict__ dw,
                                              const float* __restrict__ uw,
                                              short* __restrict__ dwb,
                                              short* __restrict__ wt2) {
    const int idx = blockIdx.x * 256 + threadIdx.x;
    if (idx < 65536) {
        dwb[idx] = f2bf(dw[idx]);
    } else {
        const int e  = idx - 65536;   // e = o*64 + kr
        const int o  = e >> 6;
        const int kr = e & 63;
        const int k  = kr >> 4, r = kr & 15;
        wt2[e] = f2bf(uw[k * 16384 + o * 16 + r]);
    }
}

// Fused LoRA: 512 blocks x 256 threads (4 waves). Block owns 32 rows (2 row-tiles).
// Wave w: rt = w&1 (row-tile), kh = w>>1 (K-half / n-half).
// Phase 1: split-K over D (each wave 512 of 1024), LDS-combine partials.
// Phase 2: split-N over output tiles (each wave 32 of 64).
__global__ void __launch_bounds__(256) lora_mfma_k(
        const float* __restrict__ hs,     // [16384][1024] f32
        const float* __restrict__ alpha,  // [4][4]
        const short* __restrict__ dwb,    // [64][1024] bf16
        const short* __restrict__ wt2,    // [1024][64] bf16
        float* __restrict__ out) {        // [16384][1024] f32
    __shared__ float pacc[2][16][64];              // split-K partials, lane-major (conflict-free)
    __shared__ __align__(16) short lowb[2][16][72];// bf16 low tiles, 16B-aligned rows

    const int t    = threadIdx.x;
    const int w    = t >> 6;
    const int lane = t & 63;
    const int rt   = w & 1;             // row-tile within block
    const int kh   = w >> 1;            // K-half (phase 1) / N-half (phase 2)
    const int fr   = lane & 15;
    const int kgi  = lane >> 4;         // 0..3
    const int kg   = kgi * 8;
    const int rowblk = blockIdx.x * 32;
    const int b      = rowblk >> 12;    // batch (blocks never straddle)
    const int myrow  = rowblk + rt * 16 + fr;

    // ---------------- phase 1: low = hs @ dwb^T (K split across wave pair) ----------------
    f32x4 acc[4];
#pragma unroll
    for (int nt = 0; nt < 4; ++nt) acc[nt] = (f32x4){0.f, 0.f, 0.f, 0.f};

    const float* ap = hs  + (size_t)myrow * D + kh * 512 + kg;
    const short* bp = dwb + fr * D          + kh * 512 + kg;

#pragma unroll
    for (int ks = 0; ks < 16; ++ks) {
        const float4 a0 = *reinterpret_cast<const float4*>(ap + ks * 32);
        const float4 a1 = *reinterpret_cast<const float4*>(ap + ks * 32 + 4);
        bf16x8 av;
        av[0] = f2bf(a0.x); av[1] = f2bf(a0.y); av[2] = f2bf(a0.z); av[3] = f2bf(a0.w);
        av[4] = f2bf(a1.x); av[5] = f2bf(a1.y); av[6] = f2bf(a1.z); av[7] = f2bf(a1.w);
#pragma unroll
        for (int nt = 0; nt < 4; ++nt) {
            const bf16x8 bv = *reinterpret_cast<const bf16x8*>(bp + nt * 16 * D + ks * 32);
            acc[nt] = __builtin_amdgcn_mfma_f32_16x16x32_bf16(av, bv, acc[nt], 0, 0, 0);
        }
    }

    // combine split-K partials; scale by alpha*4; convert to bf16 low tile
    if (kh) {
#pragma unroll
        for (int nt = 0; nt < 4; ++nt)
#pragma unroll
            for (int j = 0; j < 4; ++j)
                pacc[rt][nt * 4 + j][lane] = acc[nt][j];
    }
    __syncthreads();
    if (!kh) {
#pragma unroll
        for (int nt = 0; nt < 4; ++nt) {
            const float sc = alpha[b * 4 + nt] * 4.0f;   // NETWORK_ALPHA/RANK = 4
#pragma unroll
            for (int j = 0; j < 4; ++j) {
                const float v = (acc[nt][j] + pacc[rt][nt * 4 + j][lane]) * sc;
                lowb[rt][kgi * 4 + j][nt * 16 + fr] = f2bf(v);
            }
        }
    }
    __syncthreads();

    // ---------------- phase 2: out = low @ wt2^T (N split across wave pair) ----------------
    const bf16x8 pa0 = *reinterpret_cast<const bf16x8*>(&lowb[rt][fr][kg]);
    const bf16x8 pa1 = *reinterpret_cast<const bf16x8*>(&lowb[rt][fr][32 + kg]);

    float* op = out + (size_t)(rowblk + rt * 16 + kgi * 4) * O;
    const short* wp = wt2 + fr * 64 + kg;
    const int nt0 = kh * 32;

#pragma unroll 4
    for (int i = 0; i < 32; ++i) {
        const int nt = nt0 + i;
        const bf16x8 b0 = *reinterpret_cast<const bf16x8*>(wp + nt * 64 * 16);      // wt2 row stride 64... see note
        const bf16x8 b1 = *reinterpret_cast<const bf16x8*>(wp + nt * 64 * 16 + 32);
        f32x4 c = (f32x4){0.f, 0.f, 0.f, 0.f};
        c = __builtin_amdgcn_mfma_f32_16x16x32_bf16(pa0, b0, c, 0, 0, 0);
        c = __builtin_amdgcn_mfma_f32_16x16x32_bf16(pa1, b1, c, 0, 0, 0);
#pragma unroll
        for (int j = 0; j < 4; ++j)
            op[(size_t)j * O + nt * 16 + fr] = c[j];
    }
}

} // namespace

extern "C" void kernel_launch(void* const* d_in, const int* in_sizes, int n_in,
                              void* d_out, int out_size, void* d_ws, size_t ws_size,
                              hipStream_t stream) {
    const float* hs    = (const float*)d_in[0];  // [4,4096,1024]
    const float* alpha = (const float*)d_in[1];  // [4,4]
    const float* dw    = (const float*)d_in[2];  // [4,16,1024]
    const float* uw    = (const float*)d_in[3];  // [4,1024,16]
    short* dwb = (short*)d_ws;                   // 128 KB
    short* wt2 = dwb + 65536;                    // 128 KB
    float* outp = (float*)d_out;

    hipLaunchKernelGGL(prep_k,      dim3(512), dim3(256), 0, stream, dw, uw, dwb, wt2);
    hipLaunchKernelGGL(lora_mfma_k, dim3(512), dim3(256), 0, stream, hs, alpha, dwb, wt2, outp);
}

// Round 5
// 38.825 us; speedup vs baseline: 7.7748x; 1.3244x over previous
//
#include <hip/hip_runtime.h>

namespace {

typedef short  bf16x8 __attribute__((ext_vector_type(8)));
typedef float  f32x4  __attribute__((ext_vector_type(4)));

constexpr int D = 1024;   // in_features
constexpr int O = 1024;   // out_features

// fp32 -> bf16 bits, round-to-nearest-even
__device__ __forceinline__ short f2bf(float f) {
    unsigned u = __builtin_bit_cast(unsigned, f);
    u += 0x7fffu + ((u >> 16) & 1u);
    return (short)(u >> 16);
}

__device__ __forceinline__ bf16x8 cvt8(const float4 a, const float4 b) {
    bf16x8 v;
    v[0] = f2bf(a.x); v[1] = f2bf(a.y); v[2] = f2bf(a.z); v[3] = f2bf(a.w);
    v[4] = f2bf(b.x); v[5] = f2bf(b.y); v[6] = f2bf(b.z); v[7] = f2bf(b.w);
    return v;
}

// Fused LoRA. 256 blocks x 512 threads (8 waves). Block owns 64 rows.
// Wave w: rt = w>>1 (row-tile, 16 rows), kh = w&1 (K-half / N-half split).
// All B-operands staged in LDS (bf16, converted in-flight from the f32
// originals); inner loops are ds_read + MFMA only.
__global__ void __launch_bounds__(512) lora_mfma_k(
        const float* __restrict__ hs,     // [16384][1024] f32
        const float* __restrict__ alpha,  // [4][4]
        const float* __restrict__ dw,     // [64][1024] f32  (k*16+r major)
        const float* __restrict__ uw,     // [4][1024][16] f32
        float* __restrict__ out) {        // [16384][1024] f32
    // bs: phase-1 chunk [64][264] (33.8KB) / phase-2 chunk [256][72] (36.9KB)
    __shared__ __align__(16) short bs[18432];        // 36864 B
    __shared__ __align__(16) short lowb[4][16][72];  // 18432 B
    __shared__ float pacc[4][16][64];                // split-K partials (lane-major)

    const int t    = threadIdx.x;
    const int w    = t >> 6;
    const int lane = t & 63;
    const int rt   = w >> 1;            // row-tile 0..3
    const int kh   = w & 1;             // K-half / N-half
    const int fr   = lane & 15;
    const int kgi  = lane >> 4;         // 0..3
    const int kg   = kgi * 8;
    const int rowblk = blockIdx.x * 64;
    const int b      = rowblk >> 12;    // batch (64-row blocks never straddle)
    const int myrow  = rowblk + rt * 16 + fr;

    // ---------------- phase 1: low = hs @ dw^T (K split across wave pair) ----------------
    f32x4 acc[4];
#pragma unroll
    for (int nt = 0; nt < 4; ++nt) acc[nt] = (f32x4){0.f, 0.f, 0.f, 0.f};

#pragma unroll 1
    for (int c = 0; c < 4; ++c) {
        __syncthreads();   // previous chunk's bs reads complete
        // stage dw[0..64][c*256..+256] -> bs[kr][264], f32->bf16 in flight
#pragma unroll
        for (int i = 0; i < 4; ++i) {
            const int e  = i * 512 + t;
            const int kr = e >> 5;          // 0..63
            const int cc = e & 31;          // 16B chunk within 256-col row
            const float* sp = dw + (size_t)kr * D + c * 256 + cc * 8;
            const float4 s0 = *reinterpret_cast<const float4*>(sp);
            const float4 s1 = *reinterpret_cast<const float4*>(sp + 4);
            *reinterpret_cast<bf16x8*>(&bs[kr * 264 + cc * 8]) = cvt8(s0, s1);
        }
        __syncthreads();

        const float* ap = hs + (size_t)myrow * D + c * 256 + kh * 128 + kg;
#pragma unroll
        for (int ks = 0; ks < 4; ++ks) {
            const float4 a0 = *reinterpret_cast<const float4*>(ap + ks * 32);
            const float4 a1 = *reinterpret_cast<const float4*>(ap + ks * 32 + 4);
            const bf16x8 av = cvt8(a0, a1);
#pragma unroll
            for (int nt = 0; nt < 4; ++nt) {
                const bf16x8 bv = *reinterpret_cast<const bf16x8*>(
                    &bs[(nt * 16 + fr) * 264 + kh * 128 + ks * 32 + kg]);
                acc[nt] = __builtin_amdgcn_mfma_f32_16x16x32_bf16(av, bv, acc[nt], 0, 0, 0);
            }
        }
    }

    // combine split-K partials; scale by alpha*4; bf16 low tile in LDS
    __syncthreads();
    if (kh) {
#pragma unroll
        for (int nt = 0; nt < 4; ++nt)
#pragma unroll
            for (int j = 0; j < 4; ++j)
                pacc[rt][nt * 4 + j][lane] = acc[nt][j];
    }
    __syncthreads();
    if (!kh) {
#pragma unroll
        for (int nt = 0; nt < 4; ++nt) {
            const float sc = alpha[b * 4 + nt] * 4.0f;   // NETWORK_ALPHA/RANK = 4
#pragma unroll
            for (int j = 0; j < 4; ++j) {
                const float v = (acc[nt][j] + pacc[rt][nt * 4 + j][lane]) * sc;
                lowb[rt][kgi * 4 + j][nt * 16 + fr] = f2bf(v);
            }
        }
    }
    __syncthreads();

    // ---------------- phase 2: out = low @ up^T (N split across wave pair) ----------------
    const bf16x8 pa0 = *reinterpret_cast<const bf16x8*>(&lowb[rt][fr][kg]);
    const bf16x8 pa1 = *reinterpret_cast<const bf16x8*>(&lowb[rt][fr][32 + kg]);

    float* op = out + (size_t)(rowblk + rt * 16 + kgi * 4) * O;

#pragma unroll 1
    for (int oc = 0; oc < 4; ++oc) {
        __syncthreads();   // previous chunk's bs reads / pacc reads complete
        // stage wt2 chunk: bs[o][72] = bf16(uw[k][oc*256+o][r]), kr=k*16+r
#pragma unroll
        for (int i = 0; i < 4; ++i) {
            const int e  = i * 512 + t;
            const int o  = e >> 3;          // 0..255 (row within chunk)
            const int cc = e & 7;           // kr octet: kr = cc*8
            const int k  = cc >> 1;
            const int r0 = (cc & 1) * 8;
            const float* sp = uw + (size_t)k * 16384 + (size_t)(oc * 256 + o) * 16 + r0;
            const float4 s0 = *reinterpret_cast<const float4*>(sp);
            const float4 s1 = *reinterpret_cast<const float4*>(sp + 4);
            *reinterpret_cast<bf16x8*>(&bs[o * 72 + cc * 8]) = cvt8(s0, s1);
        }
        __syncthreads();

#pragma unroll
        for (int ntl = 0; ntl < 8; ++ntl) {
            const int nt = kh * 8 + ntl;    // n-tile within this 256-col chunk
            const bf16x8 b0 = *reinterpret_cast<const bf16x8*>(&bs[(nt * 16 + fr) * 72 + kg]);
            const bf16x8 b1 = *reinterpret_cast<const bf16x8*>(&bs[(nt * 16 + fr) * 72 + 32 + kg]);
            f32x4 c2 = (f32x4){0.f, 0.f, 0.f, 0.f};
            c2 = __builtin_amdgcn_mfma_f32_16x16x32_bf16(pa0, b0, c2, 0, 0, 0);
            c2 = __builtin_amdgcn_mfma_f32_16x16x32_bf16(pa1, b1, c2, 0, 0, 0);
#pragma unroll
            for (int j = 0; j < 4; ++j)
                op[(size_t)j * O + oc * 256 + nt * 16 + fr] = c2[j];
        }
    }
}

} // namespace

extern "C" void kernel_launch(void* const* d_in, const int* in_sizes, int n_in,
                              void* d_out, int out_size, void* d_ws, size_t ws_size,
                              hipStream_t stream) {
    const float* hs    = (const float*)d_in[0];  // [4,4096,1024]
    const float* alpha = (const float*)d_in[1];  // [4,4]
    const float* dw    = (const float*)d_in[2];  // [4,16,1024]
    const float* uw    = (const float*)d_in[3];  // [4,1024,16]
    float* outp = (float*)d_out;

    hipLaunchKernelGGL(lora_mfma_k, dim3(256), dim3(512), 0, stream,
                       hs, alpha, dw, uw, outp);
}